// Round 2
// baseline (324.433 us; speedup 1.0000x reference)
//
#include <hip/hip_runtime.h>
#include <stdint.h>

// Problem constants (B=4, N=4096, D_MODEL=1024, H=16, Dh=64, K_EIG=16)
#define NTOK   16384          // B*N tokens
#define DM     1024           // d_model (GEMM K)
#define NQKV   3072           // folded output features: [Qf|Kf|Vf], each 16*64

typedef __attribute__((ext_vector_type(8))) _Float16 half8;
typedef __attribute__((ext_vector_type(4))) _Float16 half4;
typedef __attribute__((ext_vector_type(4))) float    float4v;

__device__ __forceinline__ void async_cp16(const void* g, void* l){
  __builtin_amdgcn_global_load_lds(
      (const __attribute__((address_space(1))) void*)g,
      (__attribute__((address_space(3))) void*)l, 16, 0, 0);
}

// ---------------- x fp32 -> fp16 ----------------
__global__ void cvt_x_kernel(const float* __restrict__ x, _Float16* __restrict__ xb){
  int i = (blockIdx.x * blockDim.x + threadIdx.x) * 4;
  const int stride = gridDim.x * blockDim.x * 4;
  for(; i < NTOK * DM; i += stride){
    float4v v = *(const float4v*)(x + i);
    half4 o;
    o[0]=(_Float16)v[0]; o[1]=(_Float16)v[1]; o[2]=(_Float16)v[2]; o[3]=(_Float16)v[3];
    *(half4*)(xb + i) = o;
  }
}

// ---------------- fold E,w into weights; output pre-transposed WT[n][c] fp16 ----------------
// n = p*1024 + kE*64 + d ;  WT[n][c] = w[kE] * sum_h E[h][kE] * Wp[c][h*64+d]
__global__ void prep_w_kernel(const float* __restrict__ Wq, const float* __restrict__ Wk,
                              const float* __restrict__ Wv, const float* __restrict__ E,
                              const float* __restrict__ fw, _Float16* __restrict__ WT){
  const int nt = blockIdx.x;          // 0..47  (p*16 + kE)
  const int p  = nt >> 4, kE = nt & 15;
  const int c0 = blockIdx.y * 64;     // 0..15 tiles of 64
  const float* W = (p == 0) ? Wq : (p == 1) ? Wk : Wv;
  __shared__ _Float16 tile[64][66];   // [d][c_local], padded
  __shared__ float Ecol[16];
  const int t = threadIdx.x;
  if(t < 16) Ecol[t] = E[t * 16 + kE];
  __syncthreads();
  const float wk = fw[kE];
  const int d = t & 63, cw = t >> 6;        // lane=d -> coalesced reads
  for(int pass = 0; pass < 16; ++pass){
    const int cl = pass * 4 + cw;
    const float* row = W + (c0 + cl) * 1024 + d;
    float acc = 0.f;
    #pragma unroll
    for(int h = 0; h < 16; ++h) acc += Ecol[h] * row[h * 64];
    tile[d][cl] = (_Float16)(acc * wk);
  }
  __syncthreads();
  // coalesced write-out of transposed tile: row n = nt*64 + d2
  const int d2 = t >> 2, cb = (t & 3) * 16;
  _Float16* dst = WT + (size_t)(nt * 64 + d2) * 1024 + c0 + cb;
  #pragma unroll
  for(int j = 0; j < 16; ++j) dst[j] = tile[d2][cb + j];
}

// ---------------- folded bias fb[n] (fp32) ----------------
__global__ void prep_b_kernel(const float* __restrict__ bq, const float* __restrict__ bk,
                              const float* __restrict__ bv, const float* __restrict__ E,
                              const float* __restrict__ fw, float* __restrict__ fb){
  const int n = blockIdx.x * blockDim.x + threadIdx.x;
  if(n >= NQKV) return;
  const int p = n >> 10, kE = (n >> 6) & 15, d = n & 63;
  const float* b = (p == 0) ? bq : (p == 1) ? bk : bv;
  float acc = 0.f;
  for(int h = 0; h < 16; ++h) acc += E[h * 16 + kE] * b[h * 64 + d];
  fb[n] = acc * fw[kE];
}

// ---------------- m97-style GEMM: QKVf[m][n] = xb[m][:] . WT[n][:]  (+bias), fp16 out ----------------
__global__ __launch_bounds__(256)
void gemm_qkv_kernel(const _Float16* __restrict__ A,   // [NTOK][1024] fp16
                     const _Float16* __restrict__ BT,  // [3072][1024] fp16 (pre-transposed)
                     const float* __restrict__ bias,   // [3072] fp32
                     _Float16* __restrict__ C){        // [NTOK][3072] fp16
  __shared__ _Float16 As[128 * 32];
  __shared__ _Float16 Bs[128 * 32];
  const int t = threadIdx.x;
  const int lane = t & 63, wv = t >> 6;
  const int l15 = lane & 15, q = lane >> 4;
  const int m0 = blockIdx.y * 128, n0 = blockIdx.x * 128;
  const int wm = (wv & 1) * 64, wn = (wv >> 1) * 64;

  float4v acc[4][4];
  #pragma unroll
  for(int i = 0; i < 4; ++i)
    #pragma unroll
    for(int j = 0; j < 4; ++j){ acc[i][j][0]=0.f; acc[i][j][1]=0.f; acc[i][j][2]=0.f; acc[i][j][3]=0.f; }

  const int ar = t >> 2;            // staging row 0..63
  const int ac = (t & 3) * 8;       // staging k-offset (8 fp16 = 16B)
  const _Float16* ga0 = A  + (size_t)(m0 + ar)      * 1024 + ac;
  const _Float16* ga1 = A  + (size_t)(m0 + 64 + ar) * 1024 + ac;
  const _Float16* gb0 = BT + (size_t)(n0 + ar)      * 1024 + ac;
  const _Float16* gb1 = BT + (size_t)(n0 + 64 + ar) * 1024 + ac;

  for(int k0 = 0; k0 < 1024; k0 += 32){
    async_cp16(ga0 + k0, As + t * 8);
    async_cp16(ga1 + k0, As + 2048 + t * 8);
    async_cp16(gb0 + k0, Bs + t * 8);
    async_cp16(gb1 + k0, Bs + 2048 + t * 8);
    __syncthreads();
    half8 af[4], bf[4];
    #pragma unroll
    for(int i = 0; i < 4; ++i) af[i] = *(const half8*)(As + (wm + i * 16 + l15) * 32 + q * 8);
    #pragma unroll
    for(int j = 0; j < 4; ++j) bf[j] = *(const half8*)(Bs + (wn + j * 16 + l15) * 32 + q * 8);
    #pragma unroll
    for(int i = 0; i < 4; ++i)
      #pragma unroll
      for(int j = 0; j < 4; ++j)
        acc[i][j] = __builtin_amdgcn_mfma_f32_16x16x32_f16(af[i], bf[j], acc[i][j], 0, 0, 0);
    __syncthreads();
  }
  // epilogue: C-layout col = l15 (n), row = q*4+r (m); add folded bias, cast fp16
  #pragma unroll
  for(int j = 0; j < 4; ++j){
    const int n = n0 + wn + j * 16 + l15;
    const float bs = bias[n];
    #pragma unroll
    for(int i = 0; i < 4; ++i){
      const int mg = m0 + wm + i * 16 + q * 4;
      #pragma unroll
      for(int r = 0; r < 4; ++r)
        C[(size_t)(mg + r) * NQKV + n] = (_Float16)(acc[i][j][r] + bs);
    }
  }
}

// ---------------- per-token spectral attention: one wave per token ----------------
// S = Qf Kf^T / 8 ; P = softmax(S) ; G = E @ P ; out = G @ Vf
__global__ __launch_bounds__(256)
void attn_kernel(const _Float16* __restrict__ QKV,   // [NTOK][3072] fp16
                 const float* __restrict__ E,        // [16][16] fp32
                 float* __restrict__ out){           // [NTOK][1024] fp32
  const int t = threadIdx.x;
  const int lane = t & 63, wv = t >> 6;
  const int tok = blockIdx.x * 4 + wv;
  const int l15 = lane & 15, q = lane >> 4;
  __shared__ float Gs[4][16][20];                    // per-wave scratch

  const _Float16* base = QKV + (size_t)tok * NQKV;

  // ---- S = Qf Kf^T via 2 MFMAs, frags loaded straight from global (16B/lane, coalesced)
  half8 aq0 = *(const half8*)(base + l15 * 64 + q * 8);
  half8 aq1 = *(const half8*)(base + l15 * 64 + 32 + q * 8);
  half8 bk0 = *(const half8*)(base + 1024 + l15 * 64 + q * 8);
  half8 bk1 = *(const half8*)(base + 1024 + l15 * 64 + 32 + q * 8);
  float4v S; S[0]=0.f; S[1]=0.f; S[2]=0.f; S[3]=0.f;
  S = __builtin_amdgcn_mfma_f32_16x16x32_f16(aq0, bk0, S, 0, 0, 0);
  S = __builtin_amdgcn_mfma_f32_16x16x32_f16(aq1, bk1, S, 0, 0, 0);

  // ---- softmax over l (C-layout: col=l15 is l, row=q*4+r is k)
  float p[4];
  #pragma unroll
  for(int r = 0; r < 4; ++r){
    float v = S[r] * 0.125f;                  // / sqrt(64)
    float mx = v;
    #pragma unroll
    for(int m = 1; m < 16; m <<= 1) mx = fmaxf(mx, __shfl_xor(mx, m));
    float e = __expf(v - mx);
    float sm = e;
    #pragma unroll
    for(int m = 1; m < 16; m <<= 1) sm += __shfl_xor(sm, m);
    p[r] = e / sm;
  }

  // ---- P relayout: C-layout -> B-operand (lane n=l15 holds k=q*8+jj; k>=16 zero-padded)
  half8 pfrag;
  #pragma unroll
  for(int jj = 0; jj < 8; ++jj){
    const int k = q * 8 + jj;
    const int srcLane = ((k >> 2) & 3) * 16 + l15;
    float val = __shfl(p[jj & 3], srcLane, 64);   // src reg index jj&3 is lane-uniform
    if(q >= 2) val = 0.f;
    pfrag[jj] = (_Float16)val;
  }

  // ---- E A-operand: lane m=l15 holds k=q*8+jj (k<16 valid)
  half8 efrag;
  #pragma unroll
  for(int jj = 0; jj < 8; ++jj){
    const int k = q * 8 + jj;
    float ev = (q < 2) ? E[l15 * 16 + (k & 15)] : 0.f;
    efrag[jj] = (_Float16)ev;
  }
  float4v G; G[0]=0.f; G[1]=0.f; G[2]=0.f; G[3]=0.f;
  G = __builtin_amdgcn_mfma_f32_16x16x32_f16(efrag, pfrag, G, 0, 0, 0);

  // ---- G relayout C->A via wave-private LDS round trip
  #pragma unroll
  for(int r = 0; r < 4; ++r) Gs[wv][q * 4 + r][l15] = G[r];
  const int off = (q < 2) ? q * 8 : 0;
  float4v g0 = *(const float4v*)&Gs[wv][l15][off];
  float4v g1 = *(const float4v*)&Gs[wv][l15][off + 4];
  half8 gfrag;
  #pragma unroll
  for(int jj = 0; jj < 4; ++jj){
    gfrag[jj]     = (q < 2) ? (_Float16)g0[jj] : (_Float16)0.f;
    gfrag[jj + 4] = (q < 2) ? (_Float16)g1[jj] : (_Float16)0.f;
  }

  // ---- out = G @ Vf over 4 n-tiles of 16 (d = tt*16 + l15)
  #pragma unroll
  for(int tt = 0; tt < 4; ++tt){
    half8 vfrag;
    #pragma unroll
    for(int jj = 0; jj < 8; ++jj){
      const int k = q * 8 + jj;
      vfrag[jj] = (q < 2) ? base[2048 + (k & 15) * 64 + tt * 16 + l15] : (_Float16)0.f;
    }
    float4v O; O[0]=0.f; O[1]=0.f; O[2]=0.f; O[3]=0.f;
    O = __builtin_amdgcn_mfma_f32_16x16x32_f16(gfrag, vfrag, O, 0, 0, 0);
    #pragma unroll
    for(int r = 0; r < 4; ++r)
      out[(size_t)tok * 1024 + (q * 4 + r) * 64 + tt * 16 + l15] = O[r];
  }
}

extern "C" void kernel_launch(void* const* d_in, const int* in_sizes, int n_in,
                              void* d_out, int out_size, void* d_ws, size_t ws_size,
                              hipStream_t stream){
  const float* x  = (const float*)d_in[0];
  const float* Wq = (const float*)d_in[1];
  const float* bq = (const float*)d_in[2];
  const float* Wk = (const float*)d_in[3];
  const float* bk = (const float*)d_in[4];
  const float* Wv = (const float*)d_in[5];
  const float* bv = (const float*)d_in[6];
  const float* E  = (const float*)d_in[7];
  const float* fw = (const float*)d_in[8];
  float* out = (float*)d_out;

  // workspace layout (needs 136 MB)
  char* ws = (char*)d_ws;
  _Float16* xb  = (_Float16*)ws;                                  // 32 MB
  _Float16* WT  = (_Float16*)(ws + (size_t)32 * 1024 * 1024);     //  6 MB
  float*    fb  = (float*)   (ws + (size_t)39 * 1024 * 1024);     // 12 KB
  _Float16* QKV = (_Float16*)(ws + (size_t)40 * 1024 * 1024);     // 96 MB

  hipLaunchKernelGGL(cvt_x_kernel, dim3(4096), dim3(256), 0, stream, x, xb);
  hipLaunchKernelGGL(prep_w_kernel, dim3(48, 16), dim3(256), 0, stream, Wq, Wk, Wv, E, fw, WT);
  hipLaunchKernelGGL(prep_b_kernel, dim3(12), dim3(256), 0, stream, bq, bk, bv, E, fw, fb);
  hipLaunchKernelGGL(gemm_qkv_kernel, dim3(24, 128), dim3(256), 0, stream, xb, WT, fb, QKV);
  hipLaunchKernelGGL(attn_kernel, dim3(NTOK / 4), dim3(256), 0, stream, QKV, E, out);
}